// Round 1
// baseline (334.166 us; speedup 1.0000x reference)
//
#include <hip/hip_runtime.h>
#include <math.h>

// Problem constants (from reference setup_inputs)
#define T_TOKENS 16384
#define DIM      2048
#define NEXP     64
#define TOPK     2

#define KSPLIT   16                 // waves per block (K-split factor)
#define KCHUNK   (DIM / KSPLIT)     // 128 k's per wave

// Flat fp32 output layout: combine | topk_idx | gates | expert_activation
#define OFF_COMBINE 0
#define OFF_IDX     (T_TOKENS * NEXP)                 // 1048576
#define OFF_GATES   (OFF_IDX + T_TOKENS * TOPK)       // 1081344
#define OFF_ACT     (OFF_GATES + T_TOKENS * TOPK)     // 1114112

__global__ void zero_act_kernel(float* __restrict__ out) {
    int i = threadIdx.x;
    if (i < NEXP) out[OFF_ACT + i] = 0.0f;
}

// One block = 64 rows. 16 waves split K; lane = row within the block.
// Each lane keeps all 64 expert accumulators in VGPRs; W rows are
// wave-uniform -> scalar loads (s_load) shared across the whole grid.
__global__ __launch_bounds__(1024, 4)
void router_kernel(const float* __restrict__ x,
                   const float* __restrict__ w,      // [DIM][NEXP]
                   const float* __restrict__ noise,  // [T][NEXP]
                   float* __restrict__ out) {
    __shared__ float tile[NEXP * (NEXP + 1)];  // [row][e], pad 65 -> conflict-free
    __shared__ float bins[NEXP];

    const int tid  = threadIdx.x;
    const int lane = tid & 63;
    const int wv   = __builtin_amdgcn_readfirstlane(tid >> 6);  // uniform wave id
    const int row  = blockIdx.x * 64 + lane;
    const int k0   = wv * KCHUNK;

    float acc[NEXP];
    #pragma unroll
    for (int e = 0; e < NEXP; ++e) acc[e] = 0.0f;

    const float* __restrict__ xp = x + (size_t)row * DIM + k0;
    const float* __restrict__ wp = w + (size_t)k0 * NEXP;

    #pragma unroll 1
    for (int kk = 0; kk < KCHUNK; kk += 4) {
        const float4 xv = *reinterpret_cast<const float4*>(xp + kk);
        const float* __restrict__ wr = wp + kk * NEXP;
        #pragma unroll
        for (int u = 0; u < 4; ++u) {
            const float xs = (u == 0) ? xv.x : (u == 1) ? xv.y : (u == 2) ? xv.z : xv.w;
            #pragma unroll
            for (int e = 0; e < NEXP; ++e)
                acc[e] = fmaf(xs, wr[u * NEXP + e], acc[e]);
        }
    }

    // --- reduce the 16 K-partials in LDS ---
    for (int i = tid; i < NEXP * (NEXP + 1); i += 1024) tile[i] = 0.0f;
    if (tid < NEXP) bins[tid] = 0.0f;
    __syncthreads();

    #pragma unroll
    for (int e = 0; e < NEXP; ++e)
        atomicAdd(&tile[lane * (NEXP + 1) + e], acc[e]);
    __syncthreads();

    // --- epilogue: wave 0, one lane per row ---
    if (wv == 0) {
        const int r = lane;
        const float* __restrict__ nz = noise + (size_t)row * NEXP;

        float m1 = -1e30f, m2 = -1e30f;
        int i1 = 0, i2 = 0;
        #pragma unroll
        for (int j = 0; j < NEXP; j += 4) {
            const float4 nv = *reinterpret_cast<const float4*>(nz + j);
            float v;
            v = tile[r * (NEXP + 1) + j + 0] + nv.x;
            if (v > m1) { m2 = m1; i2 = i1; m1 = v; i1 = j + 0; } else if (v > m2) { m2 = v; i2 = j + 0; }
            v = tile[r * (NEXP + 1) + j + 1] + nv.y;
            if (v > m1) { m2 = m1; i2 = i1; m1 = v; i1 = j + 1; } else if (v > m2) { m2 = v; i2 = j + 1; }
            v = tile[r * (NEXP + 1) + j + 2] + nv.z;
            if (v > m1) { m2 = m1; i2 = i1; m1 = v; i1 = j + 2; } else if (v > m2) { m2 = v; i2 = j + 2; }
            v = tile[r * (NEXP + 1) + j + 3] + nv.w;
            if (v > m1) { m2 = m1; i2 = i1; m1 = v; i1 = j + 3; } else if (v > m2) { m2 = v; i2 = j + 3; }
        }

        // gates: softmax Z cancels under top-2 renorm -> logistic of (l2-l1)
        const float t  = expf(m2 - m1);
        const float g1 = 1.0f / (1.0f + t);
        const float g2 = 1.0f - g1;

        // combine row: zeros except the two chosen experts
        float* __restrict__ cr = out + OFF_COMBINE + (size_t)row * NEXP;
        #pragma unroll
        for (int j = 0; j < NEXP; j += 4) {
            float4 v4;
            v4.x = (j + 0 == i1) ? g1 : (j + 0 == i2) ? g2 : 0.0f;
            v4.y = (j + 1 == i1) ? g1 : (j + 1 == i2) ? g2 : 0.0f;
            v4.z = (j + 2 == i1) ? g1 : (j + 2 == i2) ? g2 : 0.0f;
            v4.w = (j + 3 == i1) ? g1 : (j + 3 == i2) ? g2 : 0.0f;
            *reinterpret_cast<float4*>(cr + j) = v4;
        }

        out[OFF_IDX + row * 2 + 0]   = (float)i1;
        out[OFF_IDX + row * 2 + 1]   = (float)i2;
        out[OFF_GATES + row * 2 + 0] = g1;
        out[OFF_GATES + row * 2 + 1] = g2;

        atomicAdd(&bins[i1], 1.0f);
        atomicAdd(&bins[i2], 1.0f);
    }
    __syncthreads();

    if (tid < NEXP) {
        const float v = bins[tid];
        if (v != 0.0f) atomicAdd(out + OFF_ACT + tid, v);
    }
}

extern "C" void kernel_launch(void* const* d_in, const int* in_sizes, int n_in,
                              void* d_out, int out_size, void* d_ws, size_t ws_size,
                              hipStream_t stream) {
    const float* x     = (const float*)d_in[0];
    const float* wg    = (const float*)d_in[1];
    const float* noise = (const float*)d_in[2];
    float* out = (float*)d_out;

    zero_act_kernel<<<1, 64, 0, stream>>>(out);
    router_kernel<<<T_TOKENS / 64, 1024, 0, stream>>>(x, wg, noise, out);
}

// Round 2
// 278.758 us; speedup vs baseline: 1.1988x; 1.1988x over previous
//
#include <hip/hip_runtime.h>
#include <math.h>

// Problem constants (from reference setup_inputs)
#define T_TOKENS 16384
#define DIM      2048
#define NEXP     64
#define TOPK     2

#define NKC   4                // K-chunks per block
#define NEG   4                // expert groups per block
#define EPG   (NEXP / NEG)     // 16 experts per group
#define KC    (DIM / NKC)      // 512 k's per wave
#define PSTR  68               // padded LDS row stride (floats); 68*4=272B, 16B-aligned

// Flat fp32 output layout: combine | topk_idx | gates | expert_activation
#define OFF_COMBINE 0
#define OFF_IDX     (T_TOKENS * NEXP)
#define OFF_GATES   (OFF_IDX + T_TOKENS * TOPK)
#define OFF_ACT     (OFF_GATES + T_TOKENS * TOPK)

__global__ void zero_act_kernel(float* __restrict__ out) {
    int i = threadIdx.x;
    if (i < NEXP) out[OFF_ACT + i] = 0.0f;
}

struct Acc { float4 a0, a1, a2, a3; };

__device__ __forceinline__ void fma16(Acc& A, float xs, const float* __restrict__ wr) {
    const float4 w0 = *reinterpret_cast<const float4*>(wr + 0);
    const float4 w1 = *reinterpret_cast<const float4*>(wr + 4);
    const float4 w2 = *reinterpret_cast<const float4*>(wr + 8);
    const float4 w3 = *reinterpret_cast<const float4*>(wr + 12);
    A.a0.x = fmaf(xs, w0.x, A.a0.x); A.a0.y = fmaf(xs, w0.y, A.a0.y);
    A.a0.z = fmaf(xs, w0.z, A.a0.z); A.a0.w = fmaf(xs, w0.w, A.a0.w);
    A.a1.x = fmaf(xs, w1.x, A.a1.x); A.a1.y = fmaf(xs, w1.y, A.a1.y);
    A.a1.z = fmaf(xs, w1.z, A.a1.z); A.a1.w = fmaf(xs, w1.w, A.a1.w);
    A.a2.x = fmaf(xs, w2.x, A.a2.x); A.a2.y = fmaf(xs, w2.y, A.a2.y);
    A.a2.z = fmaf(xs, w2.z, A.a2.z); A.a2.w = fmaf(xs, w2.w, A.a2.w);
    A.a3.x = fmaf(xs, w3.x, A.a3.x); A.a3.y = fmaf(xs, w3.y, A.a3.y);
    A.a3.z = fmaf(xs, w3.z, A.a3.z); A.a3.w = fmaf(xs, w3.w, A.a3.w);
}

// One block = 64 rows, 1024 threads = 16 waves = 4 expert-groups x 4 K-chunks.
// lane = row. 16 fp32 accumulators per lane (fits registers comfortably);
// w-row loads are wave-uniform -> scalar path.
__global__ __launch_bounds__(1024, 4)
void router_kernel(const float* __restrict__ x,
                   const float* __restrict__ w,      // [DIM][NEXP]
                   const float* __restrict__ noise,  // [T][NEXP]
                   float* __restrict__ out) {
    __shared__ float part[NKC][64][PSTR];   // ~69.6 KB partials [kc][row][e]
    __shared__ float nsh[64][PSTR];         // ~17.4 KB staged noise
    __shared__ float g1s[64], g2s[64];
    __shared__ int   i1s[64], i2s[64];
    __shared__ float bins[NEXP];

    const int tid  = threadIdx.x;
    const int lane = tid & 63;
    const int wv   = __builtin_amdgcn_readfirstlane(tid >> 6);  // uniform wave id
    const int eg   = wv & (NEG - 1);      // expert group
    const int kc   = wv >> 2;             // K chunk
    const int row  = blockIdx.x * 64 + lane;
    const int k0   = kc * KC;

    if (tid < NEXP) bins[tid] = 0.0f;

    // Stage this block's noise rows into LDS, fully coalesced.
    {
        const int r = tid >> 4, c = (tid & 15) * 4;
        const float4 nv = *reinterpret_cast<const float4*>(
            noise + (size_t)(blockIdx.x * 64 + r) * NEXP + c);
        *reinterpret_cast<float4*>(&nsh[r][c]) = nv;
    }

    Acc A;
    A.a0 = make_float4(0.f, 0.f, 0.f, 0.f);
    A.a1 = A.a0; A.a2 = A.a0; A.a3 = A.a0;

    const float* __restrict__ xp = x + (size_t)row * DIM + k0;
    const float* __restrict__ wp = w + (size_t)k0 * NEXP + eg * EPG;

    float4 xv = *reinterpret_cast<const float4*>(xp);
    #pragma unroll 1
    for (int kk = 0; kk < KC - 4; kk += 4) {
        const float4 xn = *reinterpret_cast<const float4*>(xp + kk + 4);  // prefetch
        const float* __restrict__ wr = wp + (size_t)kk * NEXP;
        fma16(A, xv.x, wr);
        fma16(A, xv.y, wr + NEXP);
        fma16(A, xv.z, wr + 2 * NEXP);
        fma16(A, xv.w, wr + 3 * NEXP);
        xv = xn;
    }
    {   // peeled last iteration
        const float* __restrict__ wr = wp + (size_t)(KC - 4) * NEXP;
        fma16(A, xv.x, wr);
        fma16(A, xv.y, wr + NEXP);
        fma16(A, xv.z, wr + 2 * NEXP);
        fma16(A, xv.w, wr + 3 * NEXP);
    }

    // Write this wave's 16-expert partial row to LDS.
    {
        float* pr = &part[kc][lane][eg * EPG];
        *reinterpret_cast<float4*>(pr + 0)  = A.a0;
        *reinterpret_cast<float4*>(pr + 4)  = A.a1;
        *reinterpret_cast<float4*>(pr + 8)  = A.a2;
        *reinterpret_cast<float4*>(pr + 12) = A.a3;
    }
    __syncthreads();

    // Epilogue: wave 0, lane = row. Sum K-partials, add noise, top-2, gates.
    if (wv == 0) {
        const int r = lane;
        float m1 = -1e30f, m2 = -1e30f;
        int i1 = 0, i2 = 0;
        #pragma unroll
        for (int j = 0; j < NEXP; j += 4) {
            float4 s        = *reinterpret_cast<const float4*>(&part[0][r][j]);
            const float4 p1 = *reinterpret_cast<const float4*>(&part[1][r][j]);
            const float4 p2 = *reinterpret_cast<const float4*>(&part[2][r][j]);
            const float4 p3 = *reinterpret_cast<const float4*>(&part[3][r][j]);
            const float4 nv = *reinterpret_cast<const float4*>(&nsh[r][j]);
            s.x += p1.x + p2.x + p3.x + nv.x;
            s.y += p1.y + p2.y + p3.y + nv.y;
            s.z += p1.z + p2.z + p3.z + nv.z;
            s.w += p1.w + p2.w + p3.w + nv.w;
            if (s.x > m1) { m2 = m1; i2 = i1; m1 = s.x; i1 = j + 0; } else if (s.x > m2) { m2 = s.x; i2 = j + 0; }
            if (s.y > m1) { m2 = m1; i2 = i1; m1 = s.y; i1 = j + 1; } else if (s.y > m2) { m2 = s.y; i2 = j + 1; }
            if (s.z > m1) { m2 = m1; i2 = i1; m1 = s.z; i1 = j + 2; } else if (s.z > m2) { m2 = s.z; i2 = j + 2; }
            if (s.w > m1) { m2 = m1; i2 = i1; m1 = s.w; i1 = j + 3; } else if (s.w > m2) { m2 = s.w; i2 = j + 3; }
        }

        // Softmax Z cancels under top-2 renorm: g1 = 1/(1+exp(l2-l1)).
        const float t  = expf(m2 - m1);
        const float g1 = 1.0f / (1.0f + t);
        const float g2 = 1.0f - g1;

        out[OFF_IDX + row * 2 + 0]   = (float)i1;
        out[OFF_IDX + row * 2 + 1]   = (float)i2;
        out[OFF_GATES + row * 2 + 0] = g1;
        out[OFF_GATES + row * 2 + 1] = g2;

        g1s[r] = g1; g2s[r] = g2; i1s[r] = i1; i2s[r] = i2;
        atomicAdd(&bins[i1], 1.0f);
        atomicAdd(&bins[i2], 1.0f);
    }
    __syncthreads();

    // Combine tile write: all 1024 threads, fully coalesced 16 KB.
    {
        const int r = tid >> 4, c = (tid & 15) * 4;
        const int   a  = i1s[r], b = i2s[r];
        const float ga = g1s[r], gb = g2s[r];
        float4 v;
        v.x = (c + 0 == a) ? ga : (c + 0 == b) ? gb : 0.0f;
        v.y = (c + 1 == a) ? ga : (c + 1 == b) ? gb : 0.0f;
        v.z = (c + 2 == a) ? ga : (c + 2 == b) ? gb : 0.0f;
        v.w = (c + 3 == a) ? ga : (c + 3 == b) ? gb : 0.0f;
        *reinterpret_cast<float4*>(
            out + OFF_COMBINE + (size_t)(blockIdx.x * 64 + r) * NEXP + c) = v;
    }

    if (tid < NEXP) {
        const float v = bins[tid];
        if (v != 0.0f) atomicAdd(out + OFF_ACT + tid, v);
    }
}

extern "C" void kernel_launch(void* const* d_in, const int* in_sizes, int n_in,
                              void* d_out, int out_size, void* d_ws, size_t ws_size,
                              hipStream_t stream) {
    const float* x     = (const float*)d_in[0];
    const float* wg    = (const float*)d_in[1];
    const float* noise = (const float*)d_in[2];
    float* out = (float*)d_out;

    zero_act_kernel<<<1, 64, 0, stream>>>(out);
    router_kernel<<<T_TOKENS / 64, 1024, 0, stream>>>(x, wg, noise, out);
}

// Round 3
// 244.504 us; speedup vs baseline: 1.3667x; 1.1401x over previous
//
#include <hip/hip_runtime.h>
#include <math.h>

// Problem constants (from reference setup_inputs)
#define T_TOKENS 16384
#define DIM      2048
#define NEXP     64
#define TOPK     2

#define NKC   4                // K-chunks per block
#define NEG   4                // expert groups per block
#define EPG   (NEXP / NEG)     // 16 experts per group
#define KC    (DIM / NKC)      // 512 k's per wave
#define PSTR  68               // padded LDS row stride (floats); 272B = 17*16B

// Flat fp32 output layout: combine | topk_idx | gates | expert_activation
#define OFF_COMBINE 0
#define OFF_IDX     (T_TOKENS * NEXP)
#define OFF_GATES   (OFF_IDX + T_TOKENS * TOPK)
#define OFF_ACT     (OFF_GATES + T_TOKENS * TOPK)

__global__ void zero_act_kernel(float* __restrict__ out) {
    int i = threadIdx.x;
    if (i < NEXP) out[OFF_ACT + i] = 0.0f;
}

struct Acc { float4 a0, a1, a2, a3; };

__device__ __forceinline__ void fma16(Acc& A, float xs, const float* __restrict__ wr) {
    const float4 w0 = *reinterpret_cast<const float4*>(wr + 0);
    const float4 w1 = *reinterpret_cast<const float4*>(wr + 4);
    const float4 w2 = *reinterpret_cast<const float4*>(wr + 8);
    const float4 w3 = *reinterpret_cast<const float4*>(wr + 12);
    A.a0.x = fmaf(xs, w0.x, A.a0.x); A.a0.y = fmaf(xs, w0.y, A.a0.y);
    A.a0.z = fmaf(xs, w0.z, A.a0.z); A.a0.w = fmaf(xs, w0.w, A.a0.w);
    A.a1.x = fmaf(xs, w1.x, A.a1.x); A.a1.y = fmaf(xs, w1.y, A.a1.y);
    A.a1.z = fmaf(xs, w1.z, A.a1.z); A.a1.w = fmaf(xs, w1.w, A.a1.w);
    A.a2.x = fmaf(xs, w2.x, A.a2.x); A.a2.y = fmaf(xs, w2.y, A.a2.y);
    A.a2.z = fmaf(xs, w2.z, A.a2.z); A.a2.w = fmaf(xs, w2.w, A.a2.w);
    A.a3.x = fmaf(xs, w3.x, A.a3.x); A.a3.y = fmaf(xs, w3.y, A.a3.y);
    A.a3.z = fmaf(xs, w3.z, A.a3.z); A.a3.w = fmaf(xs, w3.w, A.a3.w);
}

// 4 k-rows of w against one float4 of x (one quarter of a 64B x-line)
__device__ __forceinline__ void fma16x4(Acc& A, float4 xv, const float* __restrict__ wr) {
    fma16(A, xv.x, wr);
    fma16(A, xv.y, wr + NEXP);
    fma16(A, xv.z, wr + 2 * NEXP);
    fma16(A, xv.w, wr + 3 * NEXP);
}

// One block = 64 rows, 1024 threads = 16 waves = 4 expert-groups x 4 K-chunks.
// lane = row. 16 fp32 accumulators/lane. w on the scalar (s_load) path.
// x stream: 16 k's (one full 64B line) per iteration, depth-2 pipeline.
__global__ __launch_bounds__(1024, 4)
void router_kernel(const float* __restrict__ x,
                   const float* __restrict__ w,      // [DIM][NEXP]
                   const float* __restrict__ noise,  // [T][NEXP]
                   float* __restrict__ out) {
    __shared__ float part[NKC][64][PSTR];   // ~69.6 KB partials [kc][row][e]
    __shared__ float nsh[64][PSTR];         // ~17.4 KB staged noise
    __shared__ float g1s[64], g2s[64];
    __shared__ int   i1s[64], i2s[64];
    __shared__ float bins[NEXP];

    const int tid  = threadIdx.x;
    const int lane = tid & 63;
    const int wv   = __builtin_amdgcn_readfirstlane(tid >> 6);  // uniform wave id
    const int eg   = wv & (NEG - 1);      // expert group
    const int kc   = wv >> 2;             // K chunk
    const int row  = blockIdx.x * 64 + lane;
    const int k0   = kc * KC;

    if (tid < NEXP) bins[tid] = 0.0f;

    // Stage this block's noise rows into LDS, fully coalesced.
    {
        const int r = tid >> 4, c = (tid & 15) * 4;
        const float4 nv = *reinterpret_cast<const float4*>(
            noise + (size_t)(blockIdx.x * 64 + r) * NEXP + c);
        *reinterpret_cast<float4*>(&nsh[r][c]) = nv;
    }

    Acc A;
    A.a0 = make_float4(0.f, 0.f, 0.f, 0.f);
    A.a1 = A.a0; A.a2 = A.a0; A.a3 = A.a0;

    const float* __restrict__ xp = x + (size_t)row * DIM + k0;
    const float* __restrict__ wp = w + (size_t)k0 * NEXP + eg * EPG;

    // Depth-2 pipeline over 16-k bodies: X=current, Y=next, Z=prefetch.
    float4 X0 = *reinterpret_cast<const float4*>(xp + 0);
    float4 X1 = *reinterpret_cast<const float4*>(xp + 4);
    float4 X2 = *reinterpret_cast<const float4*>(xp + 8);
    float4 X3 = *reinterpret_cast<const float4*>(xp + 12);
    float4 Y0 = *reinterpret_cast<const float4*>(xp + 16);
    float4 Y1 = *reinterpret_cast<const float4*>(xp + 20);
    float4 Y2 = *reinterpret_cast<const float4*>(xp + 24);
    float4 Y3 = *reinterpret_cast<const float4*>(xp + 28);

    #pragma unroll 1
    for (int kk = 0; kk < KC; kk += 16) {
        // Prefetch kk+32 (clamped to 0 on the last two iterations: harmless
        // L1-hit reload instead of a branch).
        const int kpre = (kk + 32 < KC) ? (kk + 32) : 0;
        const float4 Z0 = *reinterpret_cast<const float4*>(xp + kpre + 0);
        const float4 Z1 = *reinterpret_cast<const float4*>(xp + kpre + 4);
        const float4 Z2 = *reinterpret_cast<const float4*>(xp + kpre + 8);
        const float4 Z3 = *reinterpret_cast<const float4*>(xp + kpre + 12);

        const float* __restrict__ wr = wp + (size_t)kk * NEXP;
        fma16x4(A, X0, wr);
        fma16x4(A, X1, wr + 4 * NEXP);
        fma16x4(A, X2, wr + 8 * NEXP);
        fma16x4(A, X3, wr + 12 * NEXP);

        X0 = Y0; X1 = Y1; X2 = Y2; X3 = Y3;
        Y0 = Z0; Y1 = Z1; Y2 = Z2; Y3 = Z3;
    }

    // Write this wave's 16-expert partial row to LDS.
    {
        float* pr = &part[kc][lane][eg * EPG];
        *reinterpret_cast<float4*>(pr + 0)  = A.a0;
        *reinterpret_cast<float4*>(pr + 4)  = A.a1;
        *reinterpret_cast<float4*>(pr + 8)  = A.a2;
        *reinterpret_cast<float4*>(pr + 12) = A.a3;
    }
    __syncthreads();

    // Epilogue: wave 0, lane = row. Sum K-partials, add noise, top-2, gates.
    if (wv == 0) {
        const int r = lane;
        float m1 = -1e30f, m2 = -1e30f;
        int i1 = 0, i2 = 0;
        #pragma unroll
        for (int j = 0; j < NEXP; j += 4) {
            float4 s        = *reinterpret_cast<const float4*>(&part[0][r][j]);
            const float4 p1 = *reinterpret_cast<const float4*>(&part[1][r][j]);
            const float4 p2 = *reinterpret_cast<const float4*>(&part[2][r][j]);
            const float4 p3 = *reinterpret_cast<const float4*>(&part[3][r][j]);
            const float4 nv = *reinterpret_cast<const float4*>(&nsh[r][j]);
            s.x += p1.x + p2.x + p3.x + nv.x;
            s.y += p1.y + p2.y + p3.y + nv.y;
            s.z += p1.z + p2.z + p3.z + nv.z;
            s.w += p1.w + p2.w + p3.w + nv.w;
            if (s.x > m1) { m2 = m1; i2 = i1; m1 = s.x; i1 = j + 0; } else if (s.x > m2) { m2 = s.x; i2 = j + 0; }
            if (s.y > m1) { m2 = m1; i2 = i1; m1 = s.y; i1 = j + 1; } else if (s.y > m2) { m2 = s.y; i2 = j + 1; }
            if (s.z > m1) { m2 = m1; i2 = i1; m1 = s.z; i1 = j + 2; } else if (s.z > m2) { m2 = s.z; i2 = j + 2; }
            if (s.w > m1) { m2 = m1; i2 = i1; m1 = s.w; i1 = j + 3; } else if (s.w > m2) { m2 = s.w; i2 = j + 3; }
        }

        // Softmax Z cancels under top-2 renorm: g1 = 1/(1+exp(l2-l1)).
        const float t  = expf(m2 - m1);
        const float g1 = 1.0f / (1.0f + t);
        const float g2 = 1.0f - g1;

        out[OFF_IDX + row * 2 + 0]   = (float)i1;
        out[OFF_IDX + row * 2 + 1]   = (float)i2;
        out[OFF_GATES + row * 2 + 0] = g1;
        out[OFF_GATES + row * 2 + 1] = g2;

        g1s[r] = g1; g2s[r] = g2; i1s[r] = i1; i2s[r] = i2;
        atomicAdd(&bins[i1], 1.0f);
        atomicAdd(&bins[i2], 1.0f);
    }
    __syncthreads();

    // Combine tile write: all 1024 threads, fully coalesced 16 KB.
    {
        const int r = tid >> 4, c = (tid & 15) * 4;
        const int   a  = i1s[r], b = i2s[r];
        const float ga = g1s[r], gb = g2s[r];
        float4 v;
        v.x = (c + 0 == a) ? ga : (c + 0 == b) ? gb : 0.0f;
        v.y = (c + 1 == a) ? ga : (c + 1 == b) ? gb : 0.0f;
        v.z = (c + 2 == a) ? ga : (c + 2 == b) ? gb : 0.0f;
        v.w = (c + 3 == a) ? ga : (c + 3 == b) ? gb : 0.0f;
        *reinterpret_cast<float4*>(
            out + OFF_COMBINE + (size_t)(blockIdx.x * 64 + r) * NEXP + c) = v;
    }

    if (tid < NEXP) {
        const float v = bins[tid];
        if (v != 0.0f) atomicAdd(out + OFF_ACT + tid, v);
    }
}

extern "C" void kernel_launch(void* const* d_in, const int* in_sizes, int n_in,
                              void* d_out, int out_size, void* d_ws, size_t ws_size,
                              hipStream_t stream) {
    const float* x     = (const float*)d_in[0];
    const float* wg    = (const float*)d_in[1];
    const float* noise = (const float*)d_in[2];
    float* out = (float*)d_out;

    zero_act_kernel<<<1, 64, 0, stream>>>(out);
    router_kernel<<<T_TOKENS / 64, 1024, 0, stream>>>(x, wg, noise, out);
}